// Round 5
// baseline (504.250 us; speedup 1.0000x reference)
//
#include <hip/hip_runtime.h>
#include <math.h>

// ---- problem dims ----
#define BB   16
#define SS   8
#define TKK  400
#define HH   256
#define EE   128
#define VV   50000
#define OOVV 50
#define HH2  512
#define STK  (SS*TKK)     // 3200
#define VOO  (VV+OOVV)    // 50050

// ---- workspace offsets (floats) ----
#define OFF_X     0        // B*E      = 2048
#define OFF_ST    2048     // B*H2     = 8192   s_t_hat = [h,c]
#define OFF_SD    10240    // B*H2     = 8192  (bias-inited in k_pre, atomic accum)
#define OFF_WD    18432    // B*H2     = 8192  (bias-inited in k_pre, atomic accum)
#define OFF_SCSEC 26752    // B*S      = 128
#define OFF_SCW   26880    // B*S*TK   = 51200
#define OFF_CT    78080    // B*H2     = 8192  (zeroed in k_pre, atomic accum)
#define OFF_OUT1  86272    // B*H      = 4096
#define OFF_PGEN  90368    // B        = 16
#define OFF_PSUM  93520    // 16*391   = 6256, layout [b][blk]
#define OFF_BT    113040   // 512*512 bf16 (512KB), LINEAR layout [round][col][kg][8]

// ---- output offsets (floats) ----
#define O_FD   0
#define O_H    800800
#define O_C    804896
#define O_CT   808992
#define O_ATTN 817184
#define O_PGEN 868384
#define O_COV  868400

#define NLB 391            // logits blocks (128 cols each)
#define GEMM_NB 1600       // 51200 rows / 32 rows-per-block

typedef __attribute__((ext_vector_type(8))) short bf16x8;
typedef __attribute__((ext_vector_type(4))) float f32x4;

__device__ __forceinline__ float sigm(float x){ return 1.0f/(1.0f+expf(-x)); }

__device__ __forceinline__ unsigned short f2b(float f){
  unsigned int u = __float_as_uint(f);
  unsigned int r = (u + 0x7fffu + ((u >> 16) & 1u)) >> 16;
  return (unsigned short)r;
}

// fast tanh: (e^2x - 1) * rcp(e^2x + 1), clamped.  abs err ~2e-7.
__device__ __forceinline__ float tanhfast(float x){
  float cx = fminf(9.0f, fmaxf(-9.0f, x));
  float t = __expf(2.0f*cx);
  return (t - 1.0f) * __builtin_amdgcn_rcpf(t + 1.0f);
}

__device__ __forceinline__ float wave_sum(float v){
  #pragma unroll
  for(int o=32;o>0;o>>=1) v += __shfl_xor(v,o);
  return v;
}
__device__ __forceinline__ float wave_max(float v){
  #pragma unroll
  for(int o=32;o>0;o>>=1) v = fmaxf(v,__shfl_xor(v,o));
  return v;
}

__device__ __forceinline__ bf16x8 cvt8(float4 a, float4 b){
  union{ bf16x8 v; unsigned short u[8]; } t;
  t.u[0]=f2b(a.x); t.u[1]=f2b(a.y); t.u[2]=f2b(a.z); t.u[3]=f2b(a.w);
  t.u[4]=f2b(b.x); t.u[5]=f2b(b.y); t.u[6]=f2b(b.z); t.u[7]=f2b(b.w);
  return t.v;
}

// ------------------------------------------------------------------
// k_pre: blocks 0..63  transpose Whw -> Btg bf16, LINEAR layout:
//        short index = rnd*16384 + col*32 + kg*8 + j   (k = rnd*32+kg*8+j)
//        One wave B-fragment read (col=base+m, kg=q) is then a contiguous
//        1KB global_load_dwordx4 — perfectly coalesced, no swizzle needed.
//        blocks 64..79 x = [c_t_1, emb[y]] @ W_xc + b_xc
//        block  80     zero CT; init SD/WD with biases (k_proj accumulates)
// grid 81 x 256
__global__ void k_pre(const float* __restrict__ Whw, unsigned short* __restrict__ Btg,
                      const int* __restrict__ y, const float* __restrict__ ct1,
                      const float* __restrict__ emb, const float* __restrict__ Wxc,
                      const float* __restrict__ bxc, const float* __restrict__ bdsec,
                      const float* __restrict__ bdw, float* __restrict__ ws){
  __shared__ float sm[10440];
  int bi = blockIdx.x, tid = threadIdx.x;
  if(bi < 64){
    int n0 = (bi & 7)*64, k0 = (bi >> 3)*64;
    int tx = tid & 63, ty = tid >> 6;  // ty 0..3
    #pragma unroll
    for(int it=0; it<16; it++){
      int kk = it*4 + ty;
      sm[kk*65 + tx] = Whw[(size_t)(k0+kk)*HH2 + n0 + tx];
    }
    __syncthreads();
    #pragma unroll
    for(int it=0; it<2; it++){
      int kgl = it*4 + ty;            // 0..7
      int kgG = (k0 >> 3) + kgl;
      int rnd = kgG >> 2, kg = kgG & 3;
      int col = n0 + tx;
      union{ bf16x8 v; unsigned short u[8]; } t;
      #pragma unroll
      for(int j=0;j<8;j++) t.u[j] = f2b(sm[(kgl*8+j)*65 + tx]);
      *(bf16x8*)&Btg[(size_t)rnd*16384 + (size_t)(col*4 + kg)*8] = t.v;
    }
  } else if(bi < 80){
    float* cat = sm;                  // [b][640]
    float* red = sm + 10240;          // 128
    for(int f=tid; f<BB*640; f+=256){
      int b = f/640, r = f - b*640;
      cat[f] = (r < HH2) ? ct1[b*HH2 + r] : emb[(size_t)y[b]*EE + (r-HH2)];
    }
    __syncthreads();
    int c = (bi-64)*8 + (tid & 7);
    int b = (tid >> 3) & 15;
    int kh = tid >> 7;                // 0..1
    float acc = 0.0f;
    const float* a = &cat[b*640];
    for(int k=kh*320; k<kh*320+320; k++) acc += a[k]*Wxc[k*EE + c];
    if(kh==1) red[b*8 + (tid&7)] = acc;
    __syncthreads();
    if(kh==0) ws[OFF_X + b*EE + c] = acc + red[b*8 + (tid&7)] + bxc[c];
  } else {
    for(int f=tid; f<BB*HH2; f+=256){
      int c = f & (HH2-1);
      ws[OFF_CT + f] = 0.0f;
      ws[OFF_SD + f] = bdsec[c];
      ws[OFF_WD + f] = bdw[c];
    }
  }
}

// ------------------------------------------------------------------
// fused LSTM.  grid 64 x 256: block = 16 j-cols x 4 b, ksplit 4
__global__ void k_lstm(const float* __restrict__ h0, const float* __restrict__ c0,
                       const float* __restrict__ Wih, const float* __restrict__ bih,
                       const float* __restrict__ Whh, const float* __restrict__ bhh,
                       float* __restrict__ ws, float* __restrict__ out){
  __shared__ float xh[4*384];
  __shared__ float red[3*64*4];
  int tid = threadIdx.x;
  int jc = (blockIdx.x & 15)*16, bc = (blockIdx.x >> 4)*4;
  for(int f=tid; f<4*384; f+=256){
    int bl = f/384, r = f - bl*384;
    xh[f] = (r < EE) ? ws[OFF_X + (bc+bl)*EE + r] : h0[(bc+bl)*HH + (r-EE)];
  }
  __syncthreads();
  int jl = tid & 15, bl = (tid >> 4) & 3, kq = tid >> 6;
  int j = jc + jl, b = bc + bl;
  float a0=0.f, a1=0.f, a2=0.f, a3=0.f;
  const float* a = &xh[bl*384];
  for(int k=kq*96; k<kq*96+96; k++){
    float v = a[k];
    const float* w = (k < EE) ? &Wih[k*4*HH + j] : &Whh[(k-EE)*4*HH + j];
    a0 += v*w[0]; a1 += v*w[HH]; a2 += v*w[2*HH]; a3 += v*w[3*HH];
  }
  if(kq){
    float* r = &red[((kq-1)*64 + bl*16 + jl)*4];
    r[0]=a0; r[1]=a1; r[2]=a2; r[3]=a3;
  }
  __syncthreads();
  if(kq==0){
    #pragma unroll
    for(int p=0;p<3;p++){
      const float* r = &red[(p*64 + bl*16 + jl)*4];
      a0+=r[0]; a1+=r[1]; a2+=r[2]; a3+=r[3];
    }
    a0 += bih[j] + bhh[j];
    a1 += bih[j+HH] + bhh[j+HH];
    a2 += bih[j+2*HH] + bhh[j+2*HH];
    a3 += bih[j+3*HH] + bhh[j+3*HH];
    float c = sigm(a1)*c0[b*HH+j] + sigm(a0)*tanhf(a2);
    float h = sigm(a3)*tanhf(c);
    out[O_H + b*HH + j] = h;
    out[O_C + b*HH + j] = c;
    ws[OFF_ST + b*HH2 + j]      = h;
    ws[OFF_ST + b*HH2 + HH + j] = c;
  }
}

// ------------------------------------------------------------------
// sd/wd projections, coalesced.  grid 64 x 256.
// block = mi(2) x cb(2: 256-col half) x kq(16: 32-k chunk).
__global__ void k_proj(const float* __restrict__ Wdsec, const float* __restrict__ Wdw,
                       float* __restrict__ ws){
  __shared__ float st[BB*32];    // [b][kk]
  int tid = threadIdx.x;
  int mi = blockIdx.x >> 5;
  int cb = (blockIdx.x >> 4) & 1;
  int kq = blockIdx.x & 15;
  int k0 = kq*32;
  for(int f=tid; f<BB*32; f+=256){
    int b = f >> 5, kk = f & 31;
    st[f] = ws[OFF_ST + b*HH2 + k0 + kk];
  }
  __syncthreads();
  int c = cb*256 + tid;
  const float* Wm = (mi ? Wdw : Wdsec) + (size_t)k0*HH2 + c;
  float acc[BB];
  #pragma unroll
  for(int b=0;b<BB;b++) acc[b] = 0.0f;
  #pragma unroll 4
  for(int kk=0;kk<32;kk++){
    float wv = Wm[(size_t)kk*HH2];
    #pragma unroll
    for(int b=0;b<BB;b++) acc[b] += st[b*32 + kk]*wv;
  }
  int dst = mi ? OFF_WD : OFF_SD;
  #pragma unroll
  for(int b=0;b<BB;b++) atomicAdd(&ws[dst + b*HH2 + c], acc[b]);
}

// ------------------------------------------------------------------
// k_gemm6 — BARRIER-FREE per-wave GEMM.
// blocks 0..1599: 32 rows x 512 cols per block, 4 waves (cg = wave id),
//   wave tile 32x128, K=512 in 16 rounds of 32.
//   - B fragments read DIRECTLY from linear Btg (L2-resident, 512KB):
//     one fragment = contiguous 1KB global_load_dwordx4 per wave.
//   - A depth-1 prefetch in two NAMED float4 sets (pA/pB), alternating over
//     a hand-written 2-round body: next-round loads issue before the
//     current-round cvt -> a full round of flight, no scratch possible.
//   - NO barriers, NO LDS, NO asm waits in the K-loop: each wave self-paced,
//     3 waves/SIMD hide L2 latency. One __syncthreads in the epilogue reduce.
// blocks 1600..1727: section attention (fp32-precise) -> SCSEC.
// grid 1728 x 256.
__global__ __launch_bounds__(256, 3) void k_gemm6(
        const float* __restrict__ A, const unsigned short* __restrict__ Btg,
        const float* __restrict__ Wcw, const float* __restrict__ vw,
        const float* __restrict__ cover,
        const float* __restrict__ sec, const float* __restrict__ Whsec,
        const float* __restrict__ vsec, float* __restrict__ ws){
  __shared__ float sm[520];
  int tid = threadIdx.x;
  if(blockIdx.x >= GEMM_NB){
    // ---- esec: one block per (b,s) row, precise fp32, 256 thr x 2 cols ----
    float* row = sm;                      // 512 floats
    float* red = sm + 512;                // 4
    int bi = blockIdx.x - GEMM_NB;        // 0..127
    int b = bi >> 3;
    row[tid]       = sec[(size_t)bi*HH2 + tid];
    row[tid + 256] = sec[(size_t)bi*HH2 + tid + 256];
    __syncthreads();
    float acc0 = 0.0f, acc1 = 0.0f;
    #pragma unroll 8
    for(int k=0;k<HH2;k++){
      float rv = row[k];
      acc0 += rv*Whsec[(size_t)k*HH2 + tid];
      acc1 += rv*Whsec[(size_t)k*HH2 + tid + 256];
    }
    float val = tanhf(acc0 + ws[OFF_SD + b*HH2 + tid])       * vsec[tid]
              + tanhf(acc1 + ws[OFF_SD + b*HH2 + tid + 256]) * vsec[tid + 256];
    val = wave_sum(val);
    if((tid&63)==0) red[tid>>6] = val;
    __syncthreads();
    if(tid==0) ws[OFF_SCSEC + bi] = red[0]+red[1]+red[2]+red[3];
    return;
  }
  // ---- gemm ----
  int cg = tid >> 6, lane = tid & 63, m = lane & 15, q = lane >> 4;
  int row0 = blockIdx.x * 32;
  int b = blockIdx.x / 100;              // 100 blocks per batch (32*100 = 3200)

  // per-lane A fragment sources: rows row0+m and row0+16+m, k-slot q
  const float* a0p = &A[(size_t)(row0 + m)*HH2 + q*8];
  const float* a1p = a0p + (size_t)16*HH2;
  // per-lane B base: fragment (col = cg*128 + cf*16 + m, kg = q)
  const unsigned short* bwp = Btg + (size_t)(cg*128 + m)*32 + q*8;

  f32x4 acc0[8], acc1[8];
  #pragma unroll
  for(int j=0;j<8;j++){ acc0[j] = (f32x4){0.f,0.f,0.f,0.f}; acc1[j] = (f32x4){0.f,0.f,0.f,0.f}; }

  float4 pA0,pA1,pA2,pA3, pB0,pB1,pB2,pB3;   // named prefetch sets only
  #define LOADA(rr, s0,s1,s2,s3) {                       \
    s0 = *(const float4*)(a0p + (rr)*32);                \
    s1 = *(const float4*)(a0p + (rr)*32 + 4);            \
    s2 = *(const float4*)(a1p + (rr)*32);                \
    s3 = *(const float4*)(a1p + (rr)*32 + 4);            \
  }
  #define ROUND(rr, s0,s1,s2,s3) {                                             \
    bf16x8 af0 = cvt8(s0, s1);                                                 \
    bf16x8 af1 = cvt8(s2, s3);                                                 \
    const unsigned short* bp_ = bwp + (size_t)(rr)*16384;                      \
    bf16x8 bv[8];                                                              \
    _Pragma("unroll")                                                          \
    for(int cf=0;cf<8;cf++) bv[cf] = *(const bf16x8*)(bp_ + cf*512);           \
    _Pragma("unroll")                                                          \
    for(int cf=0;cf<8;cf++){                                                   \
      acc0[cf] = __builtin_amdgcn_mfma_f32_16x16x32_bf16(af0, bv[cf], acc0[cf], 0,0,0); \
      acc1[cf] = __builtin_amdgcn_mfma_f32_16x16x32_bf16(af1, bv[cf], acc1[cf], 0,0,0); \
    }                                                                          \
  }

  LOADA(0, pA0,pA1,pA2,pA3);
  for(int rp=0; rp<8; rp++){
    LOADA(2*rp+1, pB0,pB1,pB2,pB3);        // prefetch odd round (before cvt of even)
    ROUND(2*rp,   pA0,pA1,pA2,pA3);
    if(rp < 7) LOADA(2*rp+2, pA0,pA1,pA2,pA3);  // prefetch next even round
    ROUND(2*rp+1, pB0,pB1,pB2,pB3);
  }
  #undef LOADA
  #undef ROUND

  // ---- epilogue: fold cols with tanh into per-row sums ----
  float cov0[4], cov1[4];
  #pragma unroll
  for(int r=0;r<4;r++){
    cov0[r] = cover[row0 + q*4 + r];
    cov1[r] = cover[row0 + 16 + q*4 + r];
  }
  float rs0[4] = {0,0,0,0}, rs1[4] = {0,0,0,0};
  #pragma unroll
  for(int j=0;j<8;j++){
    int col = cg*128 + j*16 + m;
    float wdv = ws[OFF_WD + b*HH2 + col];
    float wcv = Wcw[col], vwv = vw[col];
    #pragma unroll
    for(int r=0;r<4;r++){
      rs0[r] += tanhfast(acc0[j][r] + wdv + cov0[r]*wcv) * vwv;
      rs1[r] += tanhfast(acc1[j][r] + wdv + cov1[r]*wcv) * vwv;
    }
  }
  float* rbuf = sm;                // [cg][32 rows] = 128 floats
  #pragma unroll
  for(int r=0;r<4;r++){
    float v = rs0[r];
    v += __shfl_xor(v,1,16); v += __shfl_xor(v,2,16);
    v += __shfl_xor(v,4,16); v += __shfl_xor(v,8,16);
    if(m==0) rbuf[cg*32 + q*4 + r] = v;
    float u = rs1[r];
    u += __shfl_xor(u,1,16); u += __shfl_xor(u,2,16);
    u += __shfl_xor(u,4,16); u += __shfl_xor(u,8,16);
    if(m==0) rbuf[cg*32 + 16 + q*4 + r] = u;
  }
  __syncthreads();
  if(tid < 32)
    ws[OFF_SCW + row0 + tid] = rbuf[tid] + rbuf[32+tid] + rbuf[64+tid] + rbuf[96+tid];
}

// ------------------------------------------------------------------
// beta (inline) + attn softmax + mask + renorm + coverage out.  grid 16 x 1024
__global__ void k_attn(const float* __restrict__ mask, const float* __restrict__ cover,
                       float* __restrict__ ws, float* __restrict__ out){
  int b = blockIdx.x, tid = threadIdx.x;
  __shared__ float vals[STK];
  __shared__ float redm[16], reds[16];
  __shared__ float sc[SS];
  if(tid < SS) sc[tid] = ws[OFF_SCSEC + b*SS + tid];
  __syncthreads();
  float bm = -1e30f;
  #pragma unroll
  for(int s=0;s<SS;s++) bm = fmaxf(bm, sc[s]);
  float be[SS]; float bsum = 0.0f;
  #pragma unroll
  for(int s=0;s<SS;s++){ be[s] = expf(sc[s]-bm); bsum += be[s]; }
  #pragma unroll
  for(int s=0;s<SS;s++) be[s] /= bsum;
  int lane = tid & 63, w = tid >> 6;
  float m = -1e30f;
  for(int j=tid;j<STK;j+=1024){
    float v = be[j/TKK] * ws[OFF_SCW + b*STK + j];
    vals[j] = v; m = fmaxf(m, v);
  }
  m = wave_max(m);
  if(lane==0) redm[w] = m;
  __syncthreads();
  if(tid < 16){
    float t = redm[tid];
    #pragma unroll
    for(int o=8;o>0;o>>=1) t = fmaxf(t, __shfl_xor(t,o,16));
    if(tid==0) redm[0] = t;
  }
  __syncthreads();
  m = redm[0];
  float ssum = 0.0f;
  for(int j=tid;j<STK;j+=1024){
    float e = expf(vals[j]-m) * mask[b*STK + j];
    vals[j] = e; ssum += e;
  }
  ssum = wave_sum(ssum);
  if(lane==0) reds[w] = ssum;
  __syncthreads();
  if(tid < 16){
    float t = reds[tid];
    #pragma unroll
    for(int o=8;o>0;o>>=1) t += __shfl_xor(t,o,16);
    if(tid==0) reds[0] = t;
  }
  __syncthreads();
  float inv = 1.0f/reds[0];
  for(int j=tid;j<STK;j+=1024){
    float a = vals[j]*inv;
    out[O_ATTN + b*STK + j] = a;
    out[O_COV  + b*STK + j] = cover[b*STK + j] + a;
  }
}

// ------------------------------------------------------------------
// c_t = attn @ enc.  grid (50,16) x 256.  float4-coalesced, LDS pair-reduce,
// one atomic per col per block.
__global__ void k_ct(const float* __restrict__ enc, const float* __restrict__ out,
                     float* __restrict__ ws){
  int b = blockIdx.y, tid = threadIdx.x;
  __shared__ float a[64];
  __shared__ float part[512];
  int t0 = blockIdx.x*64;
  if(tid<64) a[tid] = out[O_ATTN + b*STK + t0 + tid];
  __syncthreads();
  int c4 = tid & 127, rh = tid >> 7;       // col-quad, row-half
  const float4* e4 = (const float4*)enc;
  size_t base = ((size_t)(b*STK + t0 + rh*32))*128 + c4;
  float4 acc = {0.f,0.f,0.f,0.f};
  #pragma unroll 8
  for(int rr=0; rr<32; rr++){
    float4 v = e4[base + (size_t)rr*128];
    float av = a[rh*32 + rr];
    acc.x += av*v.x; acc.y += av*v.y; acc.z += av*v.z; acc.w += av*v.w;
  }
  if(rh) *(float4*)&part[c4*4] = acc;
  __syncthreads();
  if(!rh){
    float4 o = *(const float4*)&part[c4*4];
    atomicAdd(&ws[OFF_CT + b*HH2 + c4*4 + 0], acc.x + o.x);
    atomicAdd(&ws[OFF_CT + b*HH2 + c4*4 + 1], acc.y + o.y);
    atomicAdd(&ws[OFF_CT + b*HH2 + c4*4 + 2], acc.z + o.z);
    atomicAdd(&ws[OFF_CT + b*HH2 + c4*4 + 3], acc.w + o.w);
  }
}

// ------------------------------------------------------------------
// out1: grid 65 x 256. blocks 0..63: 4 cols x 16 b, ksplit 4.
// block 64: p_gen + c_t output copy.
__global__ void k_out1(const float* __restrict__ Wp, const float* __restrict__ bp,
                       const float* __restrict__ Wo1, const float* __restrict__ bo1,
                       float* __restrict__ ws, float* __restrict__ out){
  __shared__ float cat[BB*768];   // 48 KB
  __shared__ float red[3*64];
  int tid = threadIdx.x;
  if(blockIdx.x == 64){
    int w = tid >> 6, lane = tid & 63;
    #pragma unroll
    for(int i=0;i<4;i++){
      int b = w*4 + i;
      float p = 0.0f;
      for(int k=lane;k<4*HH+EE;k+=64){
        float val = (k < HH2) ? ws[OFF_CT + b*HH2 + k]
                  : (k < 4*HH) ? ws[OFF_ST + b*HH2 + (k-HH2)]
                  : ws[OFF_X + b*EE + (k-4*HH)];
        p += val * Wp[k];
      }
      p = wave_sum(p);
      if(lane==0){
        float pg = sigm(p + bp[0]);
        ws[OFF_PGEN + b] = pg;
        out[O_PGEN + b]  = pg;
      }
    }
    for(int f=tid; f<BB*HH2; f+=256) out[O_CT + f] = ws[OFF_CT + f];
    return;
  }
  for(int f=tid; f<BB*768; f+=256){
    int b = f/768, r = f - b*768;
    cat[f] = (r < HH) ? ws[OFF_ST + b*HH2 + r] : ws[OFF_CT + b*HH2 + (r-HH)];
  }
  __syncthreads();
  int cl = tid & 3, bl = (tid >> 2) & 15, kq = tid >> 6;
  int c = blockIdx.x*4 + cl;
  float acc = 0.0f;
  const float* a = &cat[bl*768];
  for(int k=kq*192; k<kq*192+192; k++) acc += a[k]*Wo1[k*HH + c];
  if(kq) red[(kq-1)*64 + bl*4 + cl] = acc;
  __syncthreads();
  if(kq==0){
    acc += red[bl*4+cl] + red[64 + bl*4+cl] + red[128 + bl*4+cl];
    ws[OFF_OUT1 + bl*HH + c] = acc + bo1[c];
  }
}

// ------------------------------------------------------------------
// logits -> exp + per-block PSUM.  grid 391 x 256.
// Block = 128 cols x 16 b.  float4 W2 loads.
__global__ void k_logits(const float* __restrict__ W2, const float* __restrict__ b2,
                         float* __restrict__ ws, float* __restrict__ out){
  int tid = threadIdx.x;
  __shared__ float o1[BB*HH];        // 16 KB
  for(int i=tid;i<BB*HH/4;i+=256)
    ((float4*)o1)[i] = ((const float4*)&ws[OFF_OUT1])[i];
  __syncthreads();
  int cl = tid & 31, bq = tid >> 5;
  int c4 = blockIdx.x*128 + cl*4;
  bool ok = c4 < VV;
  int b0 = bq*2, b1 = b0+1;
  float4 acc0 = {0.f,0.f,0.f,0.f}, acc1 = {0.f,0.f,0.f,0.f};
  if(ok){
    const float* oa = &o1[b0*HH];
    const float* ob = &o1[b1*HH];
    #pragma unroll 4
    for(int k=0;k<HH;k++){
      float4 wv = *(const float4*)&W2[(size_t)k*VV + c4];
      float xa = oa[k], xb = ob[k];
      acc0.x += xa*wv.x; acc0.y += xa*wv.y; acc0.z += xa*wv.z; acc0.w += xa*wv.w;
      acc1.x += xb*wv.x; acc1.y += xb*wv.y; acc1.z += xb*wv.z; acc1.w += xb*wv.w;
    }
  }
  float bv[4] = {0,0,0,0};
  if(ok){ float4 t = *(const float4*)&b2[c4]; bv[0]=t.x; bv[1]=t.y; bv[2]=t.z; bv[3]=t.w; }
  float a0[4] = {acc0.x, acc0.y, acc0.z, acc0.w};
  float a1[4] = {acc1.x, acc1.y, acc1.z, acc1.w};
  float s0 = 0.0f, s1 = 0.0f;
  #pragma unroll
  for(int j=0;j<4;j++){
    float e0 = ok ? expf(a0[j]+bv[j]) : 0.0f;
    float e1 = ok ? expf(a1[j]+bv[j]) : 0.0f;
    if(ok){
      out[(size_t)b0*VOO + c4 + j] = e0;
      out[(size_t)b1*VOO + c4 + j] = e1;
    }
    s0 += e0; s1 += e1;
  }
  #pragma unroll
  for(int o=1;o<32;o<<=1){ s0 += __shfl_xor(s0,o,32); s1 += __shfl_xor(s1,o,32); }
  if(cl==0){
    ws[OFF_PSUM + b0*NLB + blockIdx.x] = s0;
    ws[OFF_PSUM + b1*NLB + blockIdx.x] = s1;
  }
}

// ------------------------------------------------------------------
// final_dist = p_gen * e / sum (v<V), extra_zeros tail.  grid (196,16) x 256
__global__ void k_final(const float* __restrict__ xz, float* __restrict__ ws,
                        float* __restrict__ out){
  int b = blockIdx.y;
  int v = blockIdx.x*256 + threadIdx.x;
  __shared__ float red[4];
  int lane = threadIdx.x & 63, w = threadIdx.x >> 6;
  float p = 0.0f;
  for(int i=threadIdx.x;i<NLB;i+=256) p += ws[OFF_PSUM + b*NLB + i];
  p = wave_sum(p);
  if(lane==0) red[w] = p;
  __syncthreads();
  float s = red[0]+red[1]+red[2]+red[3];
  float pg = ws[OFF_PGEN + b];
  if(v < VV)       out[(size_t)b*VOO + v] = pg * out[(size_t)b*VOO + v] / s;
  else if(v < VOO) out[(size_t)b*VOO + v] = xz[b*OOVV + (v-VV)];
}

// ------------------------------------------------------------------
// scatter-add (1-p_gen)*attn at extend-vocab indices.  grid (4,16) x 256
__global__ void k_scatter(const int* __restrict__ ebev, float* __restrict__ ws,
                          float* __restrict__ out){
  int b = blockIdx.y;
  float r = 1.0f - ws[OFF_PGEN + b];
  for(int j=blockIdx.x*256+threadIdx.x;j<STK;j+=1024){
    int idx = ebev[b*STK + j];
    atomicAdd(&out[(size_t)b*VOO + idx], r*out[O_ATTN + b*STK + j]);
  }
}

extern "C" void kernel_launch(void* const* d_in, const int* in_sizes, int n_in,
                              void* d_out, int out_size, void* d_ws, size_t ws_size,
                              hipStream_t stream){
  const int*   y     = (const int*)  d_in[0];
  const float* h0    = (const float*)d_in[1];
  const float* c0    = (const float*)d_in[2];
  const float* enc   = (const float*)d_in[3];
  const float* sec   = (const float*)d_in[4];
  const float* mask  = (const float*)d_in[5];
  const float* ct1   = (const float*)d_in[6];
  const float* xz    = (const float*)d_in[7];
  const int*   ebev  = (const int*)  d_in[8];
  const float* cover = (const float*)d_in[9];
  /* d_in[10] = gamma (unused by reference) */
  const float* emb   = (const float*)d_in[11];
  const float* Wxc   = (const float*)d_in[12];
  const float* bxc   = (const float*)d_in[13];
  const float* Wih   = (const float*)d_in[14];
  const float* bih   = (const float*)d_in[15];
  const float* Whh   = (const float*)d_in[16];
  const float* bhh   = (const float*)d_in[17];
  const float* Whsec = (const float*)d_in[18];
  const float* Wdsec = (const float*)d_in[19];
  const float* bdsec = (const float*)d_in[20];
  const float* vsec  = (const float*)d_in[21];
  const float* Whw   = (const float*)d_in[22];
  const float* Wcw   = (const float*)d_in[23];
  const float* Wdw   = (const float*)d_in[24];
  const float* bdw   = (const float*)d_in[25];
  const float* vw    = (const float*)d_in[26];
  const float* Wp    = (const float*)d_in[27];
  const float* bp    = (const float*)d_in[28];
  const float* Wo1   = (const float*)d_in[29];
  const float* bo1   = (const float*)d_in[30];
  const float* Wo2   = (const float*)d_in[31];
  const float* bo2   = (const float*)d_in[32];
  float* out = (float*)d_out;
  float* ws  = (float*)d_ws;
  unsigned short* Btg = (unsigned short*)(ws + OFF_BT);

  k_pre    <<<dim3(81),       dim3(256),  0, stream>>>(Whw, Btg, y, ct1, emb, Wxc, bxc, bdsec, bdw, ws);
  k_lstm   <<<dim3(64),       dim3(256),  0, stream>>>(h0, c0, Wih, bih, Whh, bhh, ws, out);
  k_proj   <<<dim3(64),       dim3(256),  0, stream>>>(Wdsec, Wdw, ws);
  k_gemm6  <<<dim3(1728),     dim3(256),  0, stream>>>(enc, Btg, Wcw, vw, cover, sec, Whsec, vsec, ws);
  k_attn   <<<dim3(BB),       dim3(1024), 0, stream>>>(mask, cover, ws, out);
  k_ct     <<<dim3(50,BB),    dim3(256),  0, stream>>>(enc, out, ws);
  k_out1   <<<dim3(65),       dim3(256),  0, stream>>>(Wp, bp, Wo1, bo1, ws, out);
  k_logits <<<dim3(NLB),      dim3(256),  0, stream>>>(Wo2, bo2, ws, out);
  k_final  <<<dim3(196,BB),   dim3(256),  0, stream>>>(xz, ws, out);
  k_scatter<<<dim3(4,BB),     dim3(256),  0, stream>>>(ebev, ws, out);
}

// Round 6
// 497.461 us; speedup vs baseline: 1.0136x; 1.0136x over previous
//
#include <hip/hip_runtime.h>
#include <math.h>

// ---- problem dims ----
#define BB   16
#define SS   8
#define TKK  400
#define HH   256
#define EE   128
#define VV   50000
#define OOVV 50
#define HH2  512
#define STK  (SS*TKK)     // 3200
#define VOO  (VV+OOVV)    // 50050

// ---- workspace offsets (floats) ----
#define OFF_X     0        // B*E      = 2048
#define OFF_ST    2048     // B*H2     = 8192   s_t_hat = [h,c]
#define OFF_SD    10240    // B*H2     = 8192  (bias-inited in k_pre, atomic accum)
#define OFF_WD    18432    // B*H2     = 8192  (bias-inited in k_pre, atomic accum)
#define OFF_SCSEC 26752    // B*S      = 128
#define OFF_SCW   26880    // B*S*TK   = 51200 (zeroed in k_pre, atomic accum)
#define OFF_CT    78080    // B*H2     = 8192  (zeroed in k_pre, atomic accum)
#define OFF_OUT1  86272    // B*H      = 4096
#define OFF_PGEN  90368    // B        = 16
#define OFF_PSUM  93520    // 16*391   = 6256, layout [b][blk]
#define OFF_BT    113040   // 512*512 bf16 (512KB), layout [round][col*4 + swz(kg)][8]

// ---- output offsets (floats) ----
#define O_FD   0
#define O_H    800800
#define O_C    804896
#define O_CT   808992
#define O_ATTN 817184
#define O_PGEN 868384
#define O_COV  868400

#define NLB 391            // logits blocks (128 cols each)
#define GEMM_NB 3200       // 1600 row-tiles (32 rows) x 2 col-halves

typedef __attribute__((ext_vector_type(8))) short bf16x8;
typedef __attribute__((ext_vector_type(4))) float f32x4;

__device__ __forceinline__ float sigm(float x){ return 1.0f/(1.0f+expf(-x)); }

__device__ __forceinline__ unsigned short f2b(float f){
  unsigned int u = __float_as_uint(f);
  unsigned int r = (u + 0x7fffu + ((u >> 16) & 1u)) >> 16;
  return (unsigned short)r;
}

// fast tanh: (e^2x - 1) * rcp(e^2x + 1), clamped.  abs err ~2e-7.
__device__ __forceinline__ float tanhfast(float x){
  float cx = fminf(9.0f, fmaxf(-9.0f, x));
  float t = __expf(2.0f*cx);
  return (t - 1.0f) * __builtin_amdgcn_rcpf(t + 1.0f);
}

__device__ __forceinline__ float wave_sum(float v){
  #pragma unroll
  for(int o=32;o>0;o>>=1) v += __shfl_xor(v,o);
  return v;
}
__device__ __forceinline__ float wave_max(float v){
  #pragma unroll
  for(int o=32;o>0;o>>=1) v = fmaxf(v,__shfl_xor(v,o));
  return v;
}

// async global->LDS, 16B per lane. LDS dest = wave-uniform base + lane*16.
__device__ __forceinline__ void glds16(const void* g, void* l){
  __builtin_amdgcn_global_load_lds((const __attribute__((address_space(1))) void*)g,
                                   (__attribute__((address_space(3))) void*)l, 16, 0, 0);
}

__device__ __forceinline__ bf16x8 cvt8(float4 a, float4 b){
  union{ bf16x8 v; unsigned short u[8]; } t;
  t.u[0]=f2b(a.x); t.u[1]=f2b(a.y); t.u[2]=f2b(a.z); t.u[3]=f2b(a.w);
  t.u[4]=f2b(b.x); t.u[5]=f2b(b.y); t.u[6]=f2b(b.z); t.u[7]=f2b(b.w);
  return t.v;
}

// ------------------------------------------------------------------
// k_pre: blocks 0..63  transpose Whw -> Btg bf16 (SWIZZLED round images:
//        short idx = rnd*16384 + (col*4 + (kg ^ ((col>>1)&3)))*8 + j)
//        blocks 64..79 x = [c_t_1, emb[y]] @ W_xc + b_xc
//        block  80     zero CT + SCW; init SD/WD with biases
// grid 81 x 256
__global__ void k_pre(const float* __restrict__ Whw, unsigned short* __restrict__ Btg,
                      const int* __restrict__ y, const float* __restrict__ ct1,
                      const float* __restrict__ emb, const float* __restrict__ Wxc,
                      const float* __restrict__ bxc, const float* __restrict__ bdsec,
                      const float* __restrict__ bdw, float* __restrict__ ws){
  __shared__ float sm[10440];
  int bi = blockIdx.x, tid = threadIdx.x;
  if(bi < 64){
    int n0 = (bi & 7)*64, k0 = (bi >> 3)*64;
    int tx = tid & 63, ty = tid >> 6;  // ty 0..3
    #pragma unroll
    for(int it=0; it<16; it++){
      int kk = it*4 + ty;
      sm[kk*65 + tx] = Whw[(size_t)(k0+kk)*HH2 + n0 + tx];
    }
    __syncthreads();
    #pragma unroll
    for(int it=0; it<2; it++){
      int kgl = it*4 + ty;            // 0..7
      int kgG = (k0 >> 3) + kgl;
      int rnd = kgG >> 2, kg = kgG & 3;
      int col = n0 + tx;
      union{ bf16x8 v; unsigned short u[8]; } t;
      #pragma unroll
      for(int j=0;j<8;j++) t.u[j] = f2b(sm[(kgl*8+j)*65 + tx]);
      *(bf16x8*)&Btg[(size_t)rnd*16384 + (size_t)(col*4 + (kg ^ ((col>>1)&3)))*8] = t.v;
    }
  } else if(bi < 80){
    float* cat = sm;                  // [b][640]
    float* red = sm + 10240;          // 128
    for(int f=tid; f<BB*640; f+=256){
      int b = f/640, r = f - b*640;
      cat[f] = (r < HH2) ? ct1[b*HH2 + r] : emb[(size_t)y[b]*EE + (r-HH2)];
    }
    __syncthreads();
    int c = (bi-64)*8 + (tid & 7);
    int b = (tid >> 3) & 15;
    int kh = tid >> 7;                // 0..1
    float acc = 0.0f;
    const float* a = &cat[b*640];
    for(int k=kh*320; k<kh*320+320; k++) acc += a[k]*Wxc[k*EE + c];
    if(kh==1) red[b*8 + (tid&7)] = acc;
    __syncthreads();
    if(kh==0) ws[OFF_X + b*EE + c] = acc + red[b*8 + (tid&7)] + bxc[c];
  } else {
    for(int f=tid; f<BB*HH2; f+=256){
      int c = f & (HH2-1);
      ws[OFF_CT + f] = 0.0f;
      ws[OFF_SD + f] = bdsec[c];
      ws[OFF_WD + f] = bdw[c];
    }
    for(int f=tid; f<BB*STK; f+=256) ws[OFF_SCW + f] = 0.0f;
  }
}

// ------------------------------------------------------------------
// fused LSTM.  grid 64 x 256: block = 16 j-cols x 4 b, ksplit 4
__global__ void k_lstm(const float* __restrict__ h0, const float* __restrict__ c0,
                       const float* __restrict__ Wih, const float* __restrict__ bih,
                       const float* __restrict__ Whh, const float* __restrict__ bhh,
                       float* __restrict__ ws, float* __restrict__ out){
  __shared__ float xh[4*384];
  __shared__ float red[3*64*4];
  int tid = threadIdx.x;
  int jc = (blockIdx.x & 15)*16, bc = (blockIdx.x >> 4)*4;
  for(int f=tid; f<4*384; f+=256){
    int bl = f/384, r = f - bl*384;
    xh[f] = (r < EE) ? ws[OFF_X + (bc+bl)*EE + r] : h0[(bc+bl)*HH + (r-EE)];
  }
  __syncthreads();
  int jl = tid & 15, bl = (tid >> 4) & 3, kq = tid >> 6;
  int j = jc + jl, b = bc + bl;
  float a0=0.f, a1=0.f, a2=0.f, a3=0.f;
  const float* a = &xh[bl*384];
  for(int k=kq*96; k<kq*96+96; k++){
    float v = a[k];
    const float* w = (k < EE) ? &Wih[k*4*HH + j] : &Whh[(k-EE)*4*HH + j];
    a0 += v*w[0]; a1 += v*w[HH]; a2 += v*w[2*HH]; a3 += v*w[3*HH];
  }
  if(kq){
    float* r = &red[((kq-1)*64 + bl*16 + jl)*4];
    r[0]=a0; r[1]=a1; r[2]=a2; r[3]=a3;
  }
  __syncthreads();
  if(kq==0){
    #pragma unroll
    for(int p=0;p<3;p++){
      const float* r = &red[(p*64 + bl*16 + jl)*4];
      a0+=r[0]; a1+=r[1]; a2+=r[2]; a3+=r[3];
    }
    a0 += bih[j] + bhh[j];
    a1 += bih[j+HH] + bhh[j+HH];
    a2 += bih[j+2*HH] + bhh[j+2*HH];
    a3 += bih[j+3*HH] + bhh[j+3*HH];
    float c = sigm(a1)*c0[b*HH+j] + sigm(a0)*tanhf(a2);
    float h = sigm(a3)*tanhf(c);
    out[O_H + b*HH + j] = h;
    out[O_C + b*HH + j] = c;
    ws[OFF_ST + b*HH2 + j]      = h;
    ws[OFF_ST + b*HH2 + HH + j] = c;
  }
}

// ------------------------------------------------------------------
// sd/wd projections, coalesced.  grid 64 x 256.
// block = mi(2) x cb(2: 256-col half) x kq(16: 32-k chunk).
__global__ void k_proj(const float* __restrict__ Wdsec, const float* __restrict__ Wdw,
                       float* __restrict__ ws){
  __shared__ float st[BB*32];    // [b][kk]
  int tid = threadIdx.x;
  int mi = blockIdx.x >> 5;
  int cb = (blockIdx.x >> 4) & 1;
  int kq = blockIdx.x & 15;
  int k0 = kq*32;
  for(int f=tid; f<BB*32; f+=256){
    int b = f >> 5, kk = f & 31;
    st[f] = ws[OFF_ST + b*HH2 + k0 + kk];
  }
  __syncthreads();
  int c = cb*256 + tid;
  const float* Wm = (mi ? Wdw : Wdsec) + (size_t)k0*HH2 + c;
  float acc[BB];
  #pragma unroll
  for(int b=0;b<BB;b++) acc[b] = 0.0f;
  #pragma unroll 4
  for(int kk=0;kk<32;kk++){
    float wv = Wm[(size_t)kk*HH2];
    #pragma unroll
    for(int b=0;b<BB;b++) acc[b] += st[b*32 + kk]*wv;
  }
  int dst = mi ? OFF_WD : OFF_SD;
  #pragma unroll
  for(int b=0;b<BB;b++) atomicAdd(&ws[dst + b*HH2 + c], acc[b]);
}

// ------------------------------------------------------------------
// k_gemm6 — R2's proven counted-vmcnt pipeline, quartered blocks for occupancy.
// blocks 0..3199: 32 rows x 256 cols (rt = bid>>1, ch = bid&1), 256 thr,
//   4 waves = 2 rg x 2 cg, wave tile 16x128 -> acc = 8 frags = 32 AGPR.
//   Unified regs ~90 -> ~5 waves/SIMD -> ~5 blocks/CU = 5 independent
//   barrier-groups per CU (R2 had 2) -> stage stalls overlap across blocks.
//   - B double-buffered via glds from swizzled Btg; vmcnt(6)/(2) counted waits
//     keep B(r+2)'s 4 glds + A(r+1)'s 2 loads in flight across barriers.
//   - A per-lane direct global->regs (named pa0/pa1), cvt in barrier shadow.
//   Epilogue: partial tanh*vw col-sums atomically added into zeroed SCW.
// blocks 3200..3327: section attention (fp32-precise) -> SCSEC.
// grid 3328 x 256, 32 KB LDS.
__global__ __launch_bounds__(256, 4) void k_gemm6(
        const float* __restrict__ A, const unsigned short* __restrict__ Btg,
        const float* __restrict__ Wcw, const float* __restrict__ vw,
        const float* __restrict__ cover,
        const float* __restrict__ sec, const float* __restrict__ Whsec,
        const float* __restrict__ vsec, float* __restrict__ ws){
  // shorts: Bs0[0..8191] Bs1[8192..16383]   (32 KB)
  __shared__ __align__(16) unsigned short smem[16384];
  int tid = threadIdx.x;
  if(blockIdx.x >= GEMM_NB){
    // ---- esec: one block per (b,s) row, precise fp32, 256 thr x 2 cols ----
    float* row = (float*)smem;            // 512 floats
    float* red = row + HH2;               // 4
    int bi = blockIdx.x - GEMM_NB;        // 0..127
    int b = bi >> 3;
    row[tid]       = sec[(size_t)bi*HH2 + tid];
    row[tid + 256] = sec[(size_t)bi*HH2 + tid + 256];
    __syncthreads();
    float acc0 = 0.0f, acc1 = 0.0f;
    #pragma unroll 8
    for(int k=0;k<HH2;k++){
      float rv = row[k];
      acc0 += rv*Whsec[(size_t)k*HH2 + tid];
      acc1 += rv*Whsec[(size_t)k*HH2 + tid + 256];
    }
    float val = tanhf(acc0 + ws[OFF_SD + b*HH2 + tid])       * vsec[tid]
              + tanhf(acc1 + ws[OFF_SD + b*HH2 + tid + 256]) * vsec[tid + 256];
    val = wave_sum(val);
    if((tid&63)==0) red[tid>>6] = val;
    __syncthreads();
    if(tid==0) ws[OFF_SCSEC + bi] = red[0]+red[1]+red[2]+red[3];
    return;
  }
  // ---- gemm ----
  int w = tid >> 6, lane = tid & 63, m = lane & 15, q = lane >> 4;
  int mk = (m >> 1) & 3, sw = q ^ mk;    // XOR-swizzle slot for kg reads
  int rg = w >> 1, cg = w & 1;           // 2 row-groups x 2 col-halves(128)
  int rt = blockIdx.x >> 1, ch = blockIdx.x & 1;
  int row0 = rt * 32;
  int b = rt / 100;                      // 100 row-tiles per batch

  // per-lane A fragment source: row = row0 + rg*16 + m, k-offset q*8
  const float* a0p = &A[(size_t)(row0 + rg*16 + m)*HH2 + q*8];

  f32x4 acc[8];
  #pragma unroll
  for(int j=0;j<8;j++) acc[j] = (f32x4){0.f,0.f,0.f,0.f};

  float4 pa0, pa1;                       // NAMED A-prefetch regs
  bf16x8 af;

  // stage one round's 256-col slice (16 KB) of pre-swizzled Btg
  #define GLDSB(rr, buf) {                                                     \
    const unsigned short* bsrc_ = Btg + (size_t)(rr)*16384 + (size_t)ch*8192;  \
    unsigned short* ldst_ = &smem[(size_t)(buf)*8192];                         \
    _Pragma("unroll")                                                          \
    for(int i_=0;i_<4;i_++)                                                    \
      glds16(bsrc_ + i_*2048 + tid*8, ldst_ + i_*2048 + tid*8);                \
  }
  #define LOADA(rr) {                                                          \
    pa0 = *(const float4*)(a0p + (rr)*32);                                     \
    pa1 = *(const float4*)(a0p + (rr)*32 + 4);                                 \
  }

  // ---- prologue: FIFO = [B(0)x4, A(0)x2, B(1)x4] ----
  GLDSB(0, 0);
  LOADA(0);
  GLDSB(1, 1);
  asm volatile("s_waitcnt vmcnt(6)" ::: "memory");   // B(0) landed
  __builtin_amdgcn_sched_barrier(0);
  af = cvt8(pa0, pa1);                               // compiler waits A(0)
  __builtin_amdgcn_s_barrier();                      // B(0) visible block-wide

  for(int r=0; r<16; r++){
    if(r < 15) LOADA(r+1);                           // A(r+1) early
    __builtin_amdgcn_s_setprio(1);
    #pragma unroll
    for(int cf=0; cf<8; cf++){
      int lcol = cg*128 + cf*16 + m;                 // 0..255 within slice
      bf16x8 bv = *(const bf16x8*)&smem[(size_t)(r&1)*8192 + ((size_t)lcol*4 + sw)*8];
      acc[cf] = __builtin_amdgcn_mfma_f32_16x16x32_bf16(af, bv, acc[cf], 0,0,0);
    }
    __builtin_amdgcn_s_setprio(0);
    if(r <= 13){
      asm volatile("s_waitcnt lgkmcnt(0)" ::: "memory");  // my B reads retired
      __builtin_amdgcn_sched_barrier(0);
      __builtin_amdgcn_s_barrier();                  // BAR-A: buf[r&1] free
      GLDSB(r+2, r&1);                               // B(r+2)
    }
    if(r < 15){
      if(r <= 13){ asm volatile("s_waitcnt vmcnt(6)" ::: "memory"); }
      else       { asm volatile("s_waitcnt vmcnt(2)" ::: "memory"); }
      __builtin_amdgcn_sched_barrier(0);
      af = cvt8(pa0, pa1);                           // A(r+1) in barrier shadow
      __builtin_amdgcn_s_barrier();                  // BAR-B: B(r+1) ready
    }
  }
  #undef GLDSB
  #undef LOADA

  // ---- epilogue: fold this slice's cols with tanh into per-row partials ----
  float cov[4];
  #pragma unroll
  for(int r=0;r<4;r++) cov[r] = cover[row0 + rg*16 + q*4 + r];
  float rsum[4] = {0,0,0,0};
  #pragma unroll
  for(int j=0;j<8;j++){
    int col = ch*256 + cg*128 + j*16 + m;            // global col
    float wdv = ws[OFF_WD + b*HH2 + col];
    float wcv = Wcw[col], vwv = vw[col];
    #pragma unroll
    for(int r=0;r<4;r++)
      rsum[r] += tanhfast(acc[j][r] + wdv + cov[r]*wcv) * vwv;
  }
  __syncthreads();                 // all waves past K-loop; smem reusable
  float* rbuf = (float*)smem;      // [cg][32 rows] = 64 floats
  #pragma unroll
  for(int r=0;r<4;r++){
    float v = rsum[r];
    v += __shfl_xor(v,1,16); v += __shfl_xor(v,2,16);
    v += __shfl_xor(v,4,16); v += __shfl_xor(v,8,16);
    if(m==0) rbuf[cg*32 + rg*16 + q*4 + r] = v;
  }
  __syncthreads();
  if(tid < 32)
    atomicAdd(&ws[OFF_SCW + row0 + tid], rbuf[tid] + rbuf[32 + tid]);
}

// ------------------------------------------------------------------
// beta (inline) + attn softmax + mask + renorm + coverage out.  grid 16 x 1024
__global__ void k_attn(const float* __restrict__ mask, const float* __restrict__ cover,
                       float* __restrict__ ws, float* __restrict__ out){
  int b = blockIdx.x, tid = threadIdx.x;
  __shared__ float vals[STK];
  __shared__ float redm[16], reds[16];
  __shared__ float sc[SS];
  if(tid < SS) sc[tid] = ws[OFF_SCSEC + b*SS + tid];
  __syncthreads();
  float bm = -1e30f;
  #pragma unroll
  for(int s=0;s<SS;s++) bm = fmaxf(bm, sc[s]);
  float be[SS]; float bsum = 0.0f;
  #pragma unroll
  for(int s=0;s<SS;s++){ be[s] = expf(sc[s]-bm); bsum += be[s]; }
  #pragma unroll
  for(int s=0;s<SS;s++) be[s] /= bsum;
  int lane = tid & 63, w = tid >> 6;
  float m = -1e30f;
  for(int j=tid;j<STK;j+=1024){
    float v = be[j/TKK] * ws[OFF_SCW + b*STK + j];
    vals[j] = v; m = fmaxf(m, v);
  }
  m = wave_max(m);
  if(lane==0) redm[w] = m;
  __syncthreads();
  if(tid < 16){
    float t = redm[tid];
    #pragma unroll
    for(int o=8;o>0;o>>=1) t = fmaxf(t, __shfl_xor(t,o,16));
    if(tid==0) redm[0] = t;
  }
  __syncthreads();
  m = redm[0];
  float ssum = 0.0f;
  for(int j=tid;j<STK;j+=1024){
    float e = expf(vals[j]-m) * mask[b*STK + j];
    vals[j] = e; ssum += e;
  }
  ssum = wave_sum(ssum);
  if(lane==0) reds[w] = ssum;
  __syncthreads();
  if(tid < 16){
    float t = reds[tid];
    #pragma unroll
    for(int o=8;o>0;o>>=1) t += __shfl_xor(t,o,16);
    if(tid==0) reds[0] = t;
  }
  __syncthreads();
  float inv = 1.0f/reds[0];
  for(int j=tid;j<STK;j+=1024){
    float a = vals[j]*inv;
    out[O_ATTN + b*STK + j] = a;
    out[O_COV  + b*STK + j] = cover[b*STK + j] + a;
  }
}

// ------------------------------------------------------------------
// c_t = attn @ enc.  grid (50,16) x 256.  float4-coalesced, LDS pair-reduce,
// one atomic per col per block.
__global__ void k_ct(const float* __restrict__ enc, const float* __restrict__ out,
                     float* __restrict__ ws){
  int b = blockIdx.y, tid = threadIdx.x;
  __shared__ float a[64];
  __shared__ float part[512];
  int t0 = blockIdx.x*64;
  if(tid<64) a[tid] = out[O_ATTN + b*STK + t0 + tid];
  __syncthreads();
  int c4 = tid & 127, rh = tid >> 7;       // col-quad, row-half
  const float4* e4 = (const float4*)enc;
  size_t base = ((size_t)(b*STK + t0 + rh*32))*128 + c4;
  float4 acc = {0.f,0.f,0.f,0.f};
  #pragma unroll 8
  for(int rr=0; rr<32; rr++){
    float4 v = e4[base + (size_t)rr*128];
    float av = a[rh*32 + rr];
    acc.x += av*v.x; acc.y += av*v.y; acc.z += av*v.z; acc.w += av*v.w;
  }
  if(rh) *(float4*)&part[c4*4] = acc;
  __syncthreads();
  if(!rh){
    float4 o = *(const float4*)&part[c4*4];
    atomicAdd(&ws[OFF_CT + b*HH2 + c4*4 + 0], acc.x + o.x);
    atomicAdd(&ws[OFF_CT + b*HH2 + c4*4 + 1], acc.y + o.y);
    atomicAdd(&ws[OFF_CT + b*HH2 + c4*4 + 2], acc.z + o.z);
    atomicAdd(&ws[OFF_CT + b*HH2 + c4*4 + 3], acc.w + o.w);
  }
}

// ------------------------------------------------------------------
// out1: grid 65 x 256. blocks 0..63: 4 cols x 16 b, ksplit 4.
// block 64: p_gen + c_t output copy.
__global__ void k_out1(const float* __restrict__ Wp, const float* __restrict__ bp,
                       const float* __restrict__ Wo1, const float* __restrict__ bo1,
                       float* __restrict__ ws, float* __restrict__ out){
  __shared__ float cat[BB*768];   // 48 KB
  __shared__ float red[3*64];
  int tid = threadIdx.x;
  if(blockIdx.x == 64){
    int w = tid >> 6, lane = tid & 63;
    #pragma unroll
    for(int i=0;i<4;i++){
      int b = w*4 + i;
      float p = 0.0f;
      for(int k=lane;k<4*HH+EE;k+=64){
        float val = (k < HH2) ? ws[OFF_CT + b*HH2 + k]
                  : (k < 4*HH) ? ws[OFF_ST + b*HH2 + (k-HH2)]
                  : ws[OFF_X + b*EE + (k-4*HH)];
        p += val * Wp[k];
      }
      p = wave_sum(p);
      if(lane==0){
        float pg = sigm(p + bp[0]);
        ws[OFF_PGEN + b] = pg;
        out[O_PGEN + b]  = pg;
      }
    }
    for(int f=tid; f<BB*HH2; f+=256) out[O_CT + f] = ws[OFF_CT + f];
    return;
  }
  for(int f=tid; f<BB*768; f+=256){
    int b = f/768, r = f - b*768;
    cat[f] = (r < HH) ? ws[OFF_ST + b*HH2 + r] : ws[OFF_CT + b*HH2 + (r-HH)];
  }
  __syncthreads();
  int cl = tid & 3, bl = (tid >> 2) & 15, kq = tid >> 6;
  int c = blockIdx.x*4 + cl;
  float acc = 0.0f;
  const float* a = &cat[bl*768];
  for(int k=kq*192; k<kq*192+192; k++) acc += a[k]*Wo1[k*HH + c];
  if(kq) red[(kq-1)*64 + bl*4 + cl] = acc;
  __syncthreads();
  if(kq==0){
    acc += red[bl*4+cl] + red[64 + bl*4+cl] + red[128 + bl*4+cl];
    ws[OFF_OUT1 + bl*HH + c] = acc + bo1[c];
  }
}

// ------------------------------------------------------------------
// logits -> exp + per-block PSUM.  grid 391 x 256.
// Block = 128 cols x 16 b.  float4 W2 loads.
__global__ void k_logits(const float* __restrict__ W2, const float* __restrict__ b2,
                         float* __restrict__ ws, float* __restrict__ out){
  int tid = threadIdx.x;
  __shared__ float o1[BB*HH];        // 16 KB
  for(int i=tid;i<BB*HH/4;i+=256)
    ((float4*)o1)[i] = ((const float4*)&ws[OFF_OUT1])[i];
  __syncthreads();
  int cl = tid & 31, bq = tid >> 5;
  int c4 = blockIdx.x*128 + cl*4;
  bool ok = c4 < VV;
  int b0 = bq*2, b1 = b0+1;
  float4 acc0 = {0.f,0.f,0.f,0.f}, acc1 = {0.f,0.f,0.f,0.f};
  if(ok){
    const float* oa = &o1[b0*HH];
    const float* ob = &o1[b1*HH];
    #pragma unroll 4
    for(int k=0;k<HH;k++){
      float4 wv = *(const float4*)&W2[(size_t)k*VV + c4];
      float xa = oa[k], xb = ob[k];
      acc0.x += xa*wv.x; acc0.y += xa*wv.y; acc0.z += xa*wv.z; acc0.w += xa*wv.w;
      acc1.x += xb*wv.x; acc1.y += xb*wv.y; acc1.z += xb*wv.z; acc1.w += xb*wv.w;
    }
  }
  float bv[4] = {0,0,0,0};
  if(ok){ float4 t = *(const float4*)&b2[c4]; bv[0]=t.x; bv[1]=t.y; bv[2]=t.z; bv[3]=t.w; }
  float a0[4] = {acc0.x, acc0.y, acc0.z, acc0.w};
  float a1[4] = {acc1.x, acc1.y, acc1.z, acc1.w};
  float s0 = 0.0f, s1 = 0.0f;
  #pragma unroll
  for(int j=0;j<4;j++){
    float e0 = ok ? expf(a0[j]+bv[j]) : 0.0f;
    float e1 = ok ? expf(a1[j]+bv[j]) : 0.0f;
    if(ok){
      out[(size_t)b0*VOO + c4 + j] = e0;
      out[(size_t)b1*VOO + c4 + j] = e1;
    }
    s0 += e0; s1 += e1;
  }
  #pragma unroll
  for(int o=1;o<32;o<<=1){ s0 += __shfl_xor(s0,o,32); s1 += __shfl_xor(s1,o,32); }
  if(cl==0){
    ws[OFF_PSUM + b0*NLB + blockIdx.x] = s0;
    ws[OFF_PSUM + b1*NLB + blockIdx.x] = s1;
  }
}

// ------------------------------------------------------------------
// final_dist = p_gen * e / sum (v<V), extra_zeros tail.  grid (196,16) x 256
__global__ void k_final(const float* __restrict__ xz, float* __restrict__ ws,
                        float* __restrict__ out){
  int b = blockIdx.y;
  int v = blockIdx.x*256 + threadIdx.x;
  __shared__ float red[4];
  int lane = threadIdx.x & 63, w = threadIdx.x >> 6;
  float p = 0.0f;
  for(int i=threadIdx.x;i<NLB;i+=256) p += ws[OFF_PSUM + b*NLB + i];
  p = wave_sum(p);
  if(lane==0) red[w] = p;
  __syncthreads();
  float s = red[0]+red[1]+red[2]+red[3];
  float pg = ws[OFF_PGEN + b];
  if(v < VV)       out[(size_t)b*VOO + v] = pg * out[(size_t)b*VOO + v] / s;
  else if(v < VOO) out[(size_t)b*VOO + v] = xz[b*OOVV + (v-VV)];
}

// ------------------------------------------------------------------
// scatter-add (1-p_gen)*attn at extend-vocab indices.  grid (4,16) x 256
__global__ void k_scatter(const int* __restrict__ ebev, float* __restrict__ ws,
                          float* __restrict__ out){
  int b = blockIdx.y;
  float r = 1.0f - ws[OFF_PGEN + b];
  for(int j=blockIdx.x*256+threadIdx.x;j<STK;j+=1024){
    int idx = ebev[b*STK + j];
    atomicAdd(&out[(size_t)b*VOO + idx], r*out[O_ATTN + b*STK + j]);
  }
}

extern "C" void kernel_launch(void* const* d_in, const int* in_sizes, int n_in,
                              void* d_out, int out_size, void* d_ws, size_t ws_size,
                              hipStream_t stream){
  const int*   y     = (const int*)  d_in[0];
  const float* h0    = (const float*)d_in[1];
  const float* c0    = (const float*)d_in[2];
  const float* enc   = (const float*)d_in[3];
  const float* sec   = (const float*)d_in[4];
  const float* mask  = (const float*)d_in[5];
  const float* ct1   = (const float*)d_in[6];
  const float* xz    = (const float*)d_in[7];
  const int*   ebev  = (const int*)  d_in[8];
  const float* cover = (const float*)d_in[9];
  /* d_in[10] = gamma (unused by reference) */
  const float* emb   = (const float*)d_in[11];
  const float* Wxc   = (const float*)d_in[12];
  const float* bxc   = (const float*)d_in[13];
  const float* Wih   = (const float*)d_in[14];
  const float* bih   = (const float*)d_in[15];
  const float* Whh   = (const float*)d_in[16];
  const float* bhh   = (const float*)d_in[17];
  const float* Whsec = (const float*)d_in[18];
  const float* Wdsec = (const float*)d_in[19];
  const float* bdsec = (const float*)d_in[20];
  const float* vsec  = (const float*)d_in[21];
  const float* Whw   = (const float*)d_in[22];
  const float* Wcw   = (const float*)d_in[23];
  const float* Wdw   = (const float*)d_in[24];
  const float* bdw   = (const float*)d_in[25];
  const float* vw    = (const float*)d_in[26];
  const float* Wp    = (const float*)d_in[27];
  const float* bp    = (const float*)d_in[28];
  const float* Wo1   = (const float*)d_in[29];
  const float* bo1   = (const float*)d_in[30];
  const float* Wo2   = (const float*)d_in[31];
  const float* bo2   = (const float*)d_in[32];
  float* out = (float*)d_out;
  float* ws  = (float*)d_ws;
  unsigned short* Btg = (unsigned short*)(ws + OFF_BT);

  k_pre    <<<dim3(81),       dim3(256),  0, stream>>>(Whw, Btg, y, ct1, emb, Wxc, bxc, bdsec, bdw, ws);
  k_lstm   <<<dim3(64),       dim3(256),  0, stream>>>(h0, c0, Wih, bih, Whh, bhh, ws, out);
  k_proj   <<<dim3(64),       dim3(256),  0, stream>>>(Wdsec, Wdw, ws);
  k_gemm6  <<<dim3(3328),     dim3(256),  0, stream>>>(enc, Btg, Wcw, vw, cover, sec, Whsec, vsec, ws);
  k_attn   <<<dim3(BB),       dim3(1024), 0, stream>>>(mask, cover, ws, out);
  k_ct     <<<dim3(50,BB),    dim3(256),  0, stream>>>(enc, out, ws);
  k_out1   <<<dim3(65),       dim3(256),  0, stream>>>(Wp, bp, Wo1, bo1, ws, out);
  k_logits <<<dim3(NLB),      dim3(256),  0, stream>>>(Wo2, bo2, ws, out);
  k_final  <<<dim3(196,BB),   dim3(256),  0, stream>>>(xz, ws, out);
  k_scatter<<<dim3(4,BB),     dim3(256),  0, stream>>>(ebev, ws, out);
}

// Round 8
// 466.231 us; speedup vs baseline: 1.0815x; 1.0670x over previous
//
#include <hip/hip_runtime.h>
#include <math.h>

// ---- problem dims ----
#define BB   16
#define SS   8
#define TKK  400
#define HH   256
#define EE   128
#define VV   50000
#define OOVV 50
#define HH2  512
#define STK  (SS*TKK)     // 3200
#define VOO  (VV+OOVV)    // 50050

// ---- workspace offsets (floats) ----
#define OFF_X     0        // B*E      = 2048
#define OFF_ST    2048     // B*H2     = 8192   s_t_hat = [h,c]
#define OFF_SD    10240    // B*H2     = 8192  (bias-inited in k_pre, atomic accum)
#define OFF_WD    18432    // B*H2     = 8192  (bias-inited in k_pre, atomic accum)
#define OFF_SCSEC 26752    // B*S      = 128
#define OFF_SCW   26880    // B*S*TK   = 51200 (plain stores from gemm)
#define OFF_CT    78080    // B*H2     = 8192  (zeroed in k_pre, atomic accum)
#define OFF_OUT1  86272    // B*H      = 4096
#define OFF_PGEN  90368    // B        = 16
#define OFF_PSUM  93520    // 16*391   = 6256, layout [b][blk]
#define OFF_ASUM  99776    // B        = 16 (attn softmax denominators, zeroed)
#define OFF_BT    113040   // 512*512 bf16 (512KB), layout [round][col*4 + swz(kg)][8]

// ---- output offsets (floats) ----
#define O_FD   0
#define O_H    800800
#define O_C    804896
#define O_CT   808992
#define O_ATTN 817184
#define O_PGEN 868384
#define O_COV  868400

#define NLB 391            // logits blocks (128 cols each)
#define GEMM_NB 800

typedef __attribute__((ext_vector_type(8))) short bf16x8;
typedef __attribute__((ext_vector_type(4))) float f32x4;

__device__ __forceinline__ float sigm(float x){ return 1.0f/(1.0f+expf(-x)); }

__device__ __forceinline__ unsigned short f2b(float f){
  unsigned int u = __float_as_uint(f);
  unsigned int r = (u + 0x7fffu + ((u >> 16) & 1u)) >> 16;
  return (unsigned short)r;
}

// fast tanh: (e^2x - 1) * rcp(e^2x + 1), clamped.  abs err ~2e-7.
__device__ __forceinline__ float tanhfast(float x){
  float cx = fminf(9.0f, fmaxf(-9.0f, x));
  float t = __expf(2.0f*cx);
  return (t - 1.0f) * __builtin_amdgcn_rcpf(t + 1.0f);
}

__device__ __forceinline__ float wave_sum(float v){
  #pragma unroll
  for(int o=32;o>0;o>>=1) v += __shfl_xor(v,o);
  return v;
}

// async global->LDS, 16B per lane. LDS dest = wave-uniform base + lane*16.
__device__ __forceinline__ void glds16(const void* g, void* l){
  __builtin_amdgcn_global_load_lds((const __attribute__((address_space(1))) void*)g,
                                   (__attribute__((address_space(3))) void*)l, 16, 0, 0);
}

__device__ __forceinline__ bf16x8 cvt8(float4 a, float4 b){
  union{ bf16x8 v; unsigned short u[8]; } t;
  t.u[0]=f2b(a.x); t.u[1]=f2b(a.y); t.u[2]=f2b(a.z); t.u[3]=f2b(a.w);
  t.u[4]=f2b(b.x); t.u[5]=f2b(b.y); t.u[6]=f2b(b.z); t.u[7]=f2b(b.w);
  return t.v;
}

// ------------------------------------------------------------------
// k_pre: blocks 0..63  transpose Whw -> Btg bf16 (SWIZZLED round images:
//        short idx = rnd*16384 + (col*4 + (kg ^ ((col>>1)&3)))*8 + j)
//        blocks 64..79 x = [c_t_1, emb[y]] @ W_xc + b_xc
//        block  80     zero CT + ASUM; init SD/WD with biases
// grid 81 x 256
__global__ void k_pre(const float* __restrict__ Whw, unsigned short* __restrict__ Btg,
                      const int* __restrict__ y, const float* __restrict__ ct1,
                      const float* __restrict__ emb, const float* __restrict__ Wxc,
                      const float* __restrict__ bxc, const float* __restrict__ bdsec,
                      const float* __restrict__ bdw, float* __restrict__ ws){
  __shared__ float sm[10440];
  int bi = blockIdx.x, tid = threadIdx.x;
  if(bi < 64){
    int n0 = (bi & 7)*64, k0 = (bi >> 3)*64;
    int tx = tid & 63, ty = tid >> 6;  // ty 0..3
    #pragma unroll
    for(int it=0; it<16; it++){
      int kk = it*4 + ty;
      sm[kk*65 + tx] = Whw[(size_t)(k0+kk)*HH2 + n0 + tx];
    }
    __syncthreads();
    #pragma unroll
    for(int it=0; it<2; it++){
      int kgl = it*4 + ty;            // 0..7
      int kgG = (k0 >> 3) + kgl;
      int rnd = kgG >> 2, kg = kgG & 3;
      int col = n0 + tx;
      union{ bf16x8 v; unsigned short u[8]; } t;
      #pragma unroll
      for(int j=0;j<8;j++) t.u[j] = f2b(sm[(kgl*8+j)*65 + tx]);
      *(bf16x8*)&Btg[(size_t)rnd*16384 + (size_t)(col*4 + (kg ^ ((col>>1)&3)))*8] = t.v;
    }
  } else if(bi < 80){
    float* cat = sm;                  // [b][640]
    float* red = sm + 10240;          // 128
    for(int f=tid; f<BB*640; f+=256){
      int b = f/640, r = f - b*640;
      cat[f] = (r < HH2) ? ct1[b*HH2 + r] : emb[(size_t)y[b]*EE + (r-HH2)];
    }
    __syncthreads();
    int c = (bi-64)*8 + (tid & 7);
    int b = (tid >> 3) & 15;
    int kh = tid >> 7;                // 0..1
    float acc = 0.0f;
    const float* a = &cat[b*640];
    for(int k=kh*320; k<kh*320+320; k++) acc += a[k]*Wxc[k*EE + c];
    if(kh==1) red[b*8 + (tid&7)] = acc;
    __syncthreads();
    if(kh==0) ws[OFF_X + b*EE + c] = acc + red[b*8 + (tid&7)] + bxc[c];
  } else {
    for(int f=tid; f<BB*HH2; f+=256){
      int c = f & (HH2-1);
      ws[OFF_CT + f] = 0.0f;
      ws[OFF_SD + f] = bdsec[c];
      ws[OFF_WD + f] = bdw[c];
    }
    if(tid < BB) ws[OFF_ASUM + tid] = 0.0f;
  }
}

// ------------------------------------------------------------------
// fused LSTM.  grid 64 x 256: block = 16 j-cols x 4 b, ksplit 4
__global__ void k_lstm(const float* __restrict__ h0, const float* __restrict__ c0,
                       const float* __restrict__ Wih, const float* __restrict__ bih,
                       const float* __restrict__ Whh, const float* __restrict__ bhh,
                       float* __restrict__ ws, float* __restrict__ out){
  __shared__ float xh[4*384];
  __shared__ float red[3*64*4];
  int tid = threadIdx.x;
  int jc = (blockIdx.x & 15)*16, bc = (blockIdx.x >> 4)*4;
  for(int f=tid; f<4*384; f+=256){
    int bl = f/384, r = f - bl*384;
    xh[f] = (r < EE) ? ws[OFF_X + (bc+bl)*EE + r] : h0[(bc+bl)*HH + (r-EE)];
  }
  __syncthreads();
  int jl = tid & 15, bl = (tid >> 4) & 3, kq = tid >> 6;
  int j = jc + jl, b = bc + bl;
  float a0=0.f, a1=0.f, a2=0.f, a3=0.f;
  const float* a = &xh[bl*384];
  for(int k=kq*96; k<kq*96+96; k++){
    float v = a[k];
    const float* w = (k < EE) ? &Wih[k*4*HH + j] : &Whh[(k-EE)*4*HH + j];
    a0 += v*w[0]; a1 += v*w[HH]; a2 += v*w[2*HH]; a3 += v*w[3*HH];
  }
  if(kq){
    float* r = &red[((kq-1)*64 + bl*16 + jl)*4];
    r[0]=a0; r[1]=a1; r[2]=a2; r[3]=a3;
  }
  __syncthreads();
  if(kq==0){
    #pragma unroll
    for(int p=0;p<3;p++){
      const float* r = &red[(p*64 + bl*16 + jl)*4];
      a0+=r[0]; a1+=r[1]; a2+=r[2]; a3+=r[3];
    }
    a0 += bih[j] + bhh[j];
    a1 += bih[j+HH] + bhh[j+HH];
    a2 += bih[j+2*HH] + bhh[j+2*HH];
    a3 += bih[j+3*HH] + bhh[j+3*HH];
    float c = sigm(a1)*c0[b*HH+j] + sigm(a0)*tanhf(a2);
    float h = sigm(a3)*tanhf(c);
    out[O_H + b*HH + j] = h;
    out[O_C + b*HH + j] = c;
    ws[OFF_ST + b*HH2 + j]      = h;
    ws[OFF_ST + b*HH2 + HH + j] = c;
  }
}

// ------------------------------------------------------------------
// sd/wd projections, coalesced.  grid 64 x 256.
// block = mi(2) x cb(2: 256-col half) x kq(16: 32-k chunk).
__global__ void k_proj(const float* __restrict__ Wdsec, const float* __restrict__ Wdw,
                       float* __restrict__ ws){
  __shared__ float st[BB*32];    // [b][kk]
  int tid = threadIdx.x;
  int mi = blockIdx.x >> 5;
  int cb = (blockIdx.x >> 4) & 1;
  int kq = blockIdx.x & 15;
  int k0 = kq*32;
  for(int f=tid; f<BB*32; f+=256){
    int b = f >> 5, kk = f & 31;
    st[f] = ws[OFF_ST + b*HH2 + k0 + kk];
  }
  __syncthreads();
  int c = cb*256 + tid;
  const float* Wm = (mi ? Wdw : Wdsec) + (size_t)k0*HH2 + c;
  float acc[BB];
  #pragma unroll
  for(int b=0;b<BB;b++) acc[b] = 0.0f;
  #pragma unroll 4
  for(int kk=0;kk<32;kk++){
    float wv = Wm[(size_t)kk*HH2];
    #pragma unroll
    for(int b=0;b<BB;b++) acc[b] += st[b*32 + kk]*wv;
  }
  int dst = mi ? OFF_WD : OFF_SD;
  #pragma unroll
  for(int b=0;b<BB;b++) atomicAdd(&ws[dst + b*HH2 + c], acc[b]);
}

// ------------------------------------------------------------------
// k_gemm6 — EXACT R2 kernel (best measured: 94.4 us).
// blocks 0..799: 64 rows x 512 cols, K=512, BK=32.
//   - A fragments load DIRECTLY global->regs per lane, cvt in barrier shadow.
//   - B double-buffered via global_load_lds (Btg pre-swizzled); raw s_barrier
//     + counted s_waitcnt vmcnt(6) so prefetches stay in flight.
//   8 waves = 4 row-groups x 2 col-halves (wave tile 16x256): 16 MFMA/round.
// blocks 800..927: section attention (fp32-precise) -> SCSEC.
// grid 928 x 512, 64 KB LDS -> 2 blocks/CU (16 waves).
__global__ __launch_bounds__(512, 4) void k_gemm6(
        const float* __restrict__ A, const unsigned short* __restrict__ Btg,
        const float* __restrict__ Wcw, const float* __restrict__ vw,
        const float* __restrict__ cover,
        const float* __restrict__ sec, const float* __restrict__ Whsec,
        const float* __restrict__ vsec, float* __restrict__ ws){
  // shorts: Bs0[0..16383] Bs1[16384..32767]   (64 KB)
  __shared__ __align__(16) unsigned short smem[32768];
  int tid = threadIdx.x;
  if(blockIdx.x >= GEMM_NB){
    // ---- esec: one block per (b,s) row, precise fp32 ----
    float* row = (float*)smem;            // 512 floats
    float* red = row + HH2;               // 8
    int bi = blockIdx.x - GEMM_NB;        // 0..127
    int b = bi >> 3;
    if(tid < HH2) row[tid] = sec[(size_t)bi*HH2 + tid];
    __syncthreads();
    int col = tid;                        // 0..511
    float acc = 0.0f;
    #pragma unroll 8
    for(int k=0;k<HH2;k++) acc += row[k]*Whsec[k*HH2 + col];
    float val = tanhf(acc + ws[OFF_SD + b*HH2 + col]) * vsec[col];
    val = wave_sum(val);
    if((tid&63)==0) red[tid>>6] = val;
    __syncthreads();
    if(tid==0){
      float s = 0.0f;
      #pragma unroll
      for(int i=0;i<8;i++) s += red[i];
      ws[OFF_SCSEC + bi] = s;
    }
    return;
  }
  // ---- gemm ----
  int w = tid >> 6, lane = tid & 63, m = lane & 15, q = lane >> 4;
  int mk = (m >> 1) & 3, sw = q ^ mk;    // XOR-swizzle slot for kg reads
  int rg = w >> 1, cg = w & 1;           // 4 row-groups x 2 col-halves
  int row0 = blockIdx.x * 64;
  int b = blockIdx.x / 50;               // 50 blocks per batch

  // per-lane A fragment source: row = row0 + rg*16 + m, k-offset = q*8
  const float* arow_p = &A[(size_t)(row0 + rg*16 + m)*HH2 + q*8];

  f32x4 acc[16];
  #pragma unroll
  for(int j=0;j<16;j++) acc[j] = (f32x4){0.f,0.f,0.f,0.f};

  #define GLDSB(rr, bufsel) {                                                  \
    const unsigned short* bsrc_ = Btg + (size_t)(rr)*16384;                    \
    _Pragma("unroll")                                                          \
    for(int i_=0;i_<4;i_++)                                                    \
      glds16(bsrc_ + i_*4096 + tid*8, &smem[(bufsel)*16384 + i_*4096 + tid*8]);\
  }

  // ---- prologue: FIFO = [B(0)x4, A(0)x2, B(1)x4] ----
  GLDSB(0, 0);
  float4 pa0 = *(const float4*)(arow_p);
  float4 pa1 = *(const float4*)(arow_p + 4);
  GLDSB(1, 1);
  asm volatile("s_waitcnt vmcnt(6)" ::: "memory");   // B(0) landed
  __builtin_amdgcn_sched_barrier(0);
  bf16x8 af = cvt8(pa0, pa1);                        // A(0) (compiler waits A)
  __builtin_amdgcn_s_barrier();                      // everyone's B(0) ready

  #pragma unroll
  for(int r=0; r<16; r++){
    if(r < 15){
      pa0 = *(const float4*)(arow_p + (r+1)*32);     // A(r+1) -> regs, early
      pa1 = *(const float4*)(arow_p + (r+1)*32 + 4);
    }
    __builtin_amdgcn_s_setprio(1);
    #pragma unroll
    for(int cf=0; cf<16; cf++){
      int col = cg*256 + cf*16 + m;
      bf16x8 bv = *(const bf16x8*)&smem[(size_t)(r&1)*16384 + ((size_t)col*4 + sw)*8];
      acc[cf] = __builtin_amdgcn_mfma_f32_16x16x32_bf16(af, bv, acc[cf], 0,0,0);
    }
    __builtin_amdgcn_s_setprio(0);
    if(r < 14){
      asm volatile("s_waitcnt lgkmcnt(0)" ::: "memory");  // my B reads retired
      __builtin_amdgcn_sched_barrier(0);
      __builtin_amdgcn_s_barrier();                  // BAR-A: buf[r&1] free
      GLDSB(r+2, (r&1));                             // refill it for r+2
    }
    if(r < 15){
      if(r < 14){ asm volatile("s_waitcnt vmcnt(6)" ::: "memory"); }
      else      { asm volatile("s_waitcnt vmcnt(2)" ::: "memory"); }
      __builtin_amdgcn_sched_barrier(0);
      af = cvt8(pa0, pa1);                           // A(r+1) in barrier shadow
      __builtin_amdgcn_s_barrier();                  // BAR-B: B(r+1) ready
    }
  }
  #undef GLDSB

  // ---- epilogue: fold cols with tanh into per-row sums ----
  float cov[4];
  #pragma unroll
  for(int r=0;r<4;r++) cov[r] = cover[row0 + rg*16 + q*4 + r];
  float rsum[4] = {0,0,0,0};
  #pragma unroll
  for(int j=0;j<16;j++){
    int col = cg*256 + j*16 + m;
    float wdv = ws[OFF_WD + b*HH2 + col];
    float wcv = Wcw[col], vwv = vw[col];
    #pragma unroll
    for(int r=0;r<4;r++)
      rsum[r] += tanhfast(acc[j][r] + wdv + cov[r]*wcv) * vwv;
  }
  __syncthreads();                 // smem no longer needed as B buffer
  float* rbuf = (float*)smem;      // 128 floats
  #pragma unroll
  for(int r=0;r<4;r++){
    float v = rsum[r];
    v += __shfl_xor(v,1,16); v += __shfl_xor(v,2,16);
    v += __shfl_xor(v,4,16); v += __shfl_xor(v,8,16);
    if(m==0) rbuf[cg*64 + rg*16 + q*4 + r] = v;
  }
  __syncthreads();
  if(tid < 64) ws[OFF_SCW + row0 + tid] = rbuf[tid] + rbuf[64 + tid];
}

// ------------------------------------------------------------------
// attn pass A: e = exp(beta*scw)*mask (no max shift: |beta*scw| <= ~8,
// softmax is shift-invariant) -> out[O_ATTN] unnormalized; per-b denom
// atomically accumulated into ws[OFF_ASUM].  grid (13,16) x 256 — full chip.
__global__ void k_attnA(const float* __restrict__ mask, float* __restrict__ ws,
                        float* __restrict__ out){
  int b = blockIdx.y;
  int j = blockIdx.x*256 + threadIdx.x;
  // beta softmax over 8 section scores (registers, per-thread)
  float sc[SS];
  #pragma unroll
  for(int s=0;s<SS;s++) sc[s] = ws[OFF_SCSEC + b*SS + s];
  float bm = -1e30f;
  #pragma unroll
  for(int s=0;s<SS;s++) bm = fmaxf(bm, sc[s]);
  float bsum = 0.0f;
  #pragma unroll
  for(int s=0;s<SS;s++){ sc[s] = expf(sc[s]-bm); bsum += sc[s]; }
  float e = 0.0f;
  if(j < STK){
    float be = sc[j/TKK] / bsum;
    e = expf(be * ws[OFF_SCW + b*STK + j]) * mask[b*STK + j];
    out[O_ATTN + b*STK + j] = e;
  }
  float sv = wave_sum(e);
  if((threadIdx.x & 63) == 0) atomicAdd(&ws[OFF_ASUM + b], sv);
}

// ------------------------------------------------------------------
// attn pass B + ct fused.  grid (50,16) x 256.
// Normalize 64-token chunk, write attn + coverage, then enc*attn partials
// (float4-coalesced, LDS pair-reduce, one atomic per col per block).
__global__ void k_attnB(const float* __restrict__ enc, const float* __restrict__ cover,
                        float* __restrict__ ws, float* __restrict__ out){
  int b = blockIdx.y, tid = threadIdx.x;
  __shared__ float a[64];
  __shared__ float part[512];
  int t0 = blockIdx.x*64;
  float inv = 1.0f / ws[OFF_ASUM + b];
  if(tid < 64){
    float av = out[O_ATTN + b*STK + t0 + tid] * inv;
    a[tid] = av;
    out[O_ATTN + b*STK + t0 + tid] = av;
    out[O_COV  + b*STK + t0 + tid] = cover[b*STK + t0 + tid] + av;
  }
  __syncthreads();
  int c4 = tid & 127, rh = tid >> 7;       // col-quad, row-half
  const float4* e4 = (const float4*)enc;
  size_t base = ((size_t)(b*STK + t0 + rh*32))*128 + c4;
  float4 acc = {0.f,0.f,0.f,0.f};
  #pragma unroll 8
  for(int rr=0; rr<32; rr++){
    float4 v = e4[base + (size_t)rr*128];
    float av = a[rh*32 + rr];
    acc.x += av*v.x; acc.y += av*v.y; acc.z += av*v.z; acc.w += av*v.w;
  }
  if(rh) *(float4*)&part[c4*4] = acc;
  __syncthreads();
  if(!rh){
    float4 o = *(const float4*)&part[c4*4];
    atomicAdd(&ws[OFF_CT + b*HH2 + c4*4 + 0], acc.x + o.x);
    atomicAdd(&ws[OFF_CT + b*HH2 + c4*4 + 1], acc.y + o.y);
    atomicAdd(&ws[OFF_CT + b*HH2 + c4*4 + 2], acc.z + o.z);
    atomicAdd(&ws[OFF_CT + b*HH2 + c4*4 + 3], acc.w + o.w);
  }
}

// ------------------------------------------------------------------
// out1: grid 65 x 256. blocks 0..63: 4 cols x 16 b, ksplit 4.
// block 64: p_gen + c_t output copy.
__global__ void k_out1(const float* __restrict__ Wp, const float* __restrict__ bp,
                       const float* __restrict__ Wo1, const float* __restrict__ bo1,
                       float* __restrict__ ws, float* __restrict__ out){
  __shared__ float cat[BB*768];   // 48 KB
  __shared__ float red[3*64];
  int tid = threadIdx.x;
  if(blockIdx.x == 64){
    int w = tid >> 6, lane = tid & 63;
    #pragma unroll
    for(int i=0;i<4;i++){
      int b = w*4 + i;
      float p = 0.0f;
      for(int k=lane;k<4*HH+EE;k+=64){
        float val = (k < HH2) ? ws[OFF_CT + b*HH2 + k]
                  : (k < 4*HH) ? ws[OFF_ST + b*HH2 + (k-HH2)]
                  : ws[OFF_X + b*EE + (k-4*HH)];
        p += val * Wp[k];
      }
      p = wave_sum(p);
      if(lane==0){
        float pg = sigm(p + bp[0]);
        ws[OFF_PGEN + b] = pg;
        out[O_PGEN + b]  = pg;
      }
    }
    for(int f=tid; f<BB*HH2; f+=256) out[O_CT + f] = ws[OFF_CT + f];
    return;
  }
  for(int f=tid; f<BB*768; f+=256){
    int b = f/768, r = f - b*768;
    cat[f] = (r < HH) ? ws[OFF_ST + b*HH2 + r] : ws[OFF_CT + b*HH2 + (r-HH)];
  }
  __syncthreads();
  int cl = tid & 3, bl = (tid >> 2) & 15, kq = tid >> 6;
  int c = blockIdx.x*4 + cl;
  float acc = 0.0f;
  const float* a = &cat[bl*768];
  for(int k=kq*192; k<kq*192+192; k++) acc += a[k]*Wo1[k*HH + c];
  if(kq) red[(kq-1)*64 + bl*4 + cl] = acc;
  __syncthreads();
  if(kq==0){
    acc += red[bl*4+cl] + red[64 + bl*4+cl] + red[128 + bl*4+cl];
    ws[OFF_OUT1 + bl*HH + c] = acc + bo1[c];
  }
}

// ------------------------------------------------------------------
// logits -> exp + per-block PSUM.  grid 391 x 256.
// Block = 128 cols x 16 b.  float4 W2 loads.
__global__ void k_logits(const float* __restrict__ W2, const float* __restrict__ b2,
                         float* __restrict__ ws, float* __restrict__ out){
  int tid = threadIdx.x;
  __shared__ float o1[BB*HH];        // 16 KB
  for(int i=tid;i<BB*HH/4;i+=256)
    ((float4*)o1)[i] = ((const float4*)&ws[OFF_OUT1])[i];
  __syncthreads();
  int cl = tid & 31, bq = tid >> 5;
  int c4 = blockIdx.x*128 + cl*4;
  bool ok = c4 < VV;
  int b0 = bq*2, b1 = b0+1;
  float4 acc0 = {0.f,0.f,0.f,0.f}, acc1 = {0.f,0.f,0.f,0.f};
  if(ok){
    const float* oa = &o1[b0*HH];
    const float* ob = &o1[b1*HH];
    #pragma unroll 4
    for(int k=0;k<HH;k++){
      float4 wv = *(const float4*)&W2[(size_t)k*VV + c4];
      float xa = oa[k], xb = ob[k];
      acc0.x += xa*wv.x; acc0.y += xa*wv.y; acc0.z += xa*wv.z; acc0.w += xa*wv.w;
      acc1.x += xb*wv.x; acc1.y += xb*wv.y; acc1.z += xb*wv.z; acc1.w += xb*wv.w;
    }
  }
  float bv[4] = {0,0,0,0};
  if(ok){ float4 t = *(const float4*)&b2[c4]; bv[0]=t.x; bv[1]=t.y; bv[2]=t.z; bv[3]=t.w; }
  float a0[4] = {acc0.x, acc0.y, acc0.z, acc0.w};
  float a1[4] = {acc1.x, acc1.y, acc1.z, acc1.w};
  float s0 = 0.0f, s1 = 0.0f;
  #pragma unroll
  for(int j=0;j<4;j++){
    float e0 = ok ? expf(a0[j]+bv[j]) : 0.0f;
    float e1 = ok ? expf(a1[j]+bv[j]) : 0.0f;
    if(ok){
      out[(size_t)b0*VOO + c4 + j] = e0;
      out[(size_t)b1*VOO + c4 + j] = e1;
    }
    s0 += e0; s1 += e1;
  }
  #pragma unroll
  for(int o=1;o<32;o<<=1){ s0 += __shfl_xor(s0,o,32); s1 += __shfl_xor(s1,o,32); }
  if(cl==0){
    ws[OFF_PSUM + b0*NLB + blockIdx.x] = s0;
    ws[OFF_PSUM + b1*NLB + blockIdx.x] = s1;
  }
}

// ------------------------------------------------------------------
// final_dist = p_gen * e / sum (v<V), extra_zeros tail.  grid (196,16) x 256
__global__ void k_final(const float* __restrict__ xz, float* __restrict__ ws,
                        float* __restrict__ out){
  int b = blockIdx.y;
  int v = blockIdx.x*256 + threadIdx.x;
  __shared__ float red[4];
  int lane = threadIdx.x & 63, w = threadIdx.x >> 6;
  float p = 0.0f;
  for(int i=threadIdx.x;i<NLB;i+=256) p += ws[OFF_PSUM + b*NLB + i];
  p = wave_sum(p);
  if(lane==0) red[w] = p;
  __syncthreads();
  float s = red[0]+red[1]+red[2]+red[3];
  float pg = ws[OFF_PGEN + b];
  if(v < VV)       out[(size_t)b*VOO + v] = pg * out[(size_t)b*VOO + v] / s;
  else if(v < VOO) out[(size_t)b*VOO + v] = xz[b*OOVV + (v-VV)];
}

// ------------------------------------------------------------------
// scatter-add (1-p_gen)*attn at extend-vocab indices.  grid (4,16) x 256
__global__ void k_scatter(const int* __restrict__ ebev, float* __restrict__ ws,
                          float* __restrict__ out){
  int b = blockIdx.y;
  float r = 1.0f - ws[OFF_PGEN + b];
  for(int j=blockIdx.x*256+threadIdx.x;j<STK;j+=1024){
    int idx = ebev[b*STK + j];
    atomicAdd(&out[(size_t)b*VOO + idx], r*out[O_ATTN + b*STK + j]);
  }
}

extern "C" void kernel_launch(void* const* d_in, const int* in_sizes, int n_in,
                              void* d_out, int out_size, void* d_ws, size_t ws_size,
                              hipStream_t stream){
  const int*   y     = (const int*)  d_in[0];
  const float* h0    = (const float*)d_in[1];
  const float* c0    = (const float*)d_in[2];
  const float* enc   = (const float*)d_in[3];
  const float* sec   = (const float*)d_in[4];
  const float* mask  = (const float*)d_in[5];
  const float* ct1   = (const float*)d_in[6];
  const float* xz    = (const float*)d_in[7];
  const int*   ebev  = (const int*)  d_in[8];
  const float* cover = (const float*)d_in[9];
  /* d_in[10] = gamma (unused by reference) */
  const float* emb   = (const float*)d_in[11];
  const float* Wxc   = (const float*)d_in[12];
  const float* bxc   = (const float*)d_in[13];
  const float* Wih   = (const float*)d_in[14];
  const float* bih   = (const float*)d_in[15];
  const float* Whh   = (const float*)d_in[16];
  const float* bhh   = (const float*)d_in[17];
  const float* Whsec = (const float*)d_in[18];
  const float* Wdsec = (const float*)d_in[19];
  const float* bdsec = (const float*)d_in[20];
  const float* vsec  = (const float*)d_in[21];
  const float* Whw   = (const float*)d_in[22];
  const float* Wcw   = (const float*)d_in[23];
  const float* Wdw   = (const float*)d_in[24];
  const float* bdw   = (const float*)d_in[25];
  const float* vw    = (const float*)d_in[26];
  const float* Wp    = (const float*)d_in[27];
  const float* bp    = (const float*)d_in[28];
  const float* Wo1   = (const float*)d_in[29];
  const float* bo1   = (const float*)d_in[30];
  const float* Wo2   = (const float*)d_in[31];
  const float* bo2   = (const float*)d_in[32];
  float* out = (float*)d_out;
  float* ws  = (float*)d_ws;
  unsigned short* Btg = (unsigned short*)(ws + OFF_BT);

  k_pre    <<<dim3(81),       dim3(256),  0, stream>>>(Whw, Btg, y, ct1, emb, Wxc, bxc, bdsec, bdw, ws);
  k_lstm   <<<dim3(64),       dim3(256),  0, stream>>>(h0, c0, Wih, bih, Whh, bhh, ws, out);
  k_proj   <<<dim3(64),       dim3(256),  0, stream>>>(Wdsec, Wdw, ws);
  k_gemm6  <<<dim3(928),      dim3(512),  0, stream>>>(enc, Btg, Wcw, vw, cover, sec, Whsec, vsec, ws);
  k_attnA  <<<dim3(13,BB),    dim3(256),  0, stream>>>(mask, ws, out);
  k_attnB  <<<dim3(50,BB),    dim3(256),  0, stream>>>(enc, cover, ws, out);
  k_out1   <<<dim3(65),       dim3(256),  0, stream>>>(Wp, bp, Wo1, bo1, ws, out);
  k_logits <<<dim3(NLB),      dim3(256),  0, stream>>>(Wo2, bo2, ws, out);
  k_final  <<<dim3(196,BB),   dim3(256),  0, stream>>>(xz, ws, out);
  k_scatter<<<dim3(4,BB),     dim3(256),  0, stream>>>(ebev, ws, out);
}